// Round 16
// baseline (262.773 us; speedup 1.0000x reference)
//
#include <hip/hip_runtime.h>
#include <limits.h>

// Segment-argmax one-hot, round 14: register-batched loads + decoupled
// linear write stream + winner scatter. Plus one ablation dispatch
// (read+reduce only -> d_ws) to split read-rate from write-rate in rocprof.
//   d_in[0] = x       float32[33554432]
//   d_in[1] = sizes   int32  [262144]  (64..193, mean 128)
//   d_out   = one-hot float32[33554432]
//
// History: four structures (wave/seg 141, lane-gather ~113, LDS-staged 105,
// LDS-atomic 95, group16 95) all ~95-105us at 27% HBM with healthy occupancy
// -> diagnosis: low memory-level parallelism (runtime-trip-count load loops
// serialize to ~1 outstanding load/wave; store phase gated on full reduce).
// Fix: (1) fully-unrolled clamp-indexed float4 loads (3 independent loads in
// flight/wave); (2) writes become a block-linear zero stream (fillBuffer-
// style, proven 5.6 TB/s) + 16 scattered 1.0f after a barrier.

__global__ void scan_stage1(const int* __restrict__ sizes,
                            int* __restrict__ offs,
                            int* __restrict__ blocksums, int B) {
    int tid = threadIdx.x;
    int gid = blockIdx.x * 256 + tid;
    int v = (gid < B) ? sizes[gid] : 0;
    int lane = tid & 63;
    int incl = v;
    #pragma unroll
    for (int off = 1; off < 64; off <<= 1) {
        int n = __shfl_up(incl, off, 64);
        if (lane >= off) incl += n;
    }
    __shared__ int wsum[4];
    if (lane == 63) wsum[tid >> 6] = incl;
    __syncthreads();
    int base = 0;
    int wv = tid >> 6;
    for (int i = 0; i < wv; ++i) base += wsum[i];
    if (gid < B) offs[gid] = base + incl - v;            // exclusive within 256-chunk
    if (tid == 255) blocksums[blockIdx.x] = base + incl; // chunk total
}

__global__ void scan_stage2(int* __restrict__ blocksums, int nb) {
    int tid = threadIdx.x;   // 1024 threads, nb <= 1024
    int v = (tid < nb) ? blocksums[tid] : 0;
    int lane = tid & 63;
    int incl = v;
    #pragma unroll
    for (int off = 1; off < 64; off <<= 1) {
        int n = __shfl_up(incl, off, 64);
        if (lane >= off) incl += n;
    }
    __shared__ int wsum[16];
    if (lane == 63) wsum[tid >> 6] = incl;
    __syncthreads();
    int base = 0;
    int wv = tid >> 6;
    for (int i = 0; i < wv; ++i) base += wsum[i];
    if (tid < nb) blocksums[tid] = base + incl - v;      // in-place exclusive
}

// read + reduce for one segment via a 16-lane group; returns winner LOCAL idx
// on lane r==0 (valid there only). All loads batched & independent.
__device__ __forceinline__ int group_argmax(
        const float* __restrict__ x, int start, int size, int r) {
    const float NEG = -__builtin_inff();
    int h = (4 - (start & 3)) & 3;           // size>=63 => h<size always
    const int m4 = (size - h) >> 2;          // 15..48
    const int tl = size - h - (m4 << 2);     // 0..3

    const float4* __restrict__ p4 = reinterpret_cast<const float4*>(x + start + h);
    const int k0 = r, k1 = r + 16, k2 = r + 32;
    // clamp-indexed, unconditionally issued -> 3 loads in flight
    float4 v0 = p4[k0 < m4 ? k0 : 0];
    float4 v1 = p4[k1 < m4 ? k1 : 0];
    float4 v2 = p4[k2 < m4 ? k2 : 0];
    float hv = (r < h)  ? x[start + r] : NEG;
    float tv = (r < tl) ? x[start + h + (m4 << 2) + r] : NEG;
    if (k0 >= m4) { v0.x = NEG; v0.y = NEG; v0.z = NEG; v0.w = NEG; }
    if (k1 >= m4) { v1.x = NEG; v1.y = NEG; v1.z = NEG; v1.w = NEG; }
    if (k2 >= m4) { v2.x = NEG; v2.y = NEG; v2.z = NEG; v2.w = NEG; }

    float best = NEG; int bi = INT_MAX;
    #define UPD(vv, ii) do { float _v = (vv); int _i = (ii); \
        if (_v > best || (_v == best && _i < bi)) { best = _v; bi = _i; } } while (0)
    UPD(hv, r);                               // head idx r < h <= body idxs
    int b0 = h + (k0 << 2);
    UPD(v0.x, b0); UPD(v0.y, b0 + 1); UPD(v0.z, b0 + 2); UPD(v0.w, b0 + 3);
    int b1 = h + (k1 << 2);
    UPD(v1.x, b1); UPD(v1.y, b1 + 1); UPD(v1.z, b1 + 2); UPD(v1.w, b1 + 3);
    int b2 = h + (k2 << 2);
    UPD(v2.x, b2); UPD(v2.y, b2 + 1); UPD(v2.z, b2 + 2); UPD(v2.w, b2 + 3);
    UPD(tv, h + (m4 << 2) + r);
    #undef UPD

    #pragma unroll
    for (int m = 1; m <= 8; m <<= 1) {        // 16-lane butterfly, first-max
        const float ov = __shfl_xor(best, m, 64);
        const int   oi = __shfl_xor(bi, m, 64);
        if (ov > best || (ov == best && oi < bi)) { best = ov; bi = oi; }
    }
    return bi;
}

__global__ __launch_bounds__(256) void seg16_onehot2(
        const float* __restrict__ x,
        const int* __restrict__ sizes,
        const int* __restrict__ offs,
        const int* __restrict__ blockoffs,
        float* __restrict__ out, int B) {
    __shared__ int winner[16];
    const int t = threadIdx.x;
    const int g = t >> 4, r = t & 15;
    const int s0 = blockIdx.x * 16;          // B % 16 == 0
    const int s  = s0 + g;
    const int bo = blockoffs[blockIdx.x >> 4];
    const int start = offs[s] + bo;
    const int size  = sizes[s];

    const int bi = group_argmax(x, start, size, r);
    if (r == 0) winner[g] = start + bi;      // absolute winner index
    __syncthreads();

    // block-linear zero stream over the exact span [s_abs, e_abs)
    const int s_abs = offs[s0] + bo;
    const int lastS = s0 + 15;
    const int e_abs = offs[lastS] + bo + sizes[lastS];
    const int a4 = (s_abs + 3) & ~3;
    const int e4 = e_abs & ~3;
    const int nh = a4 - s_abs, nt = e_abs - e4;
    if (t < nh) out[s_abs + t] = 0.0f;
    float4* __restrict__ o4 = reinterpret_cast<float4*>(out + a4);
    const int nb4 = (e4 - a4) >> 2;          // ~515
    const float4 z4 = make_float4(0.f, 0.f, 0.f, 0.f);
    for (int j = t; j < nb4; j += 256) o4[j] = z4;
    if (t < nt) out[e4 + t] = 0.0f;
    __syncthreads();                         // drains zero-stores (vmcnt) first

    if (t < 16) out[winner[t]] = 1.0f;       // span-local: no cross-block race
}

// ablation: identical read+reduce, NO output stream (winners -> d_ws)
__global__ __launch_bounds__(256) void abl_read(
        const float* __restrict__ x,
        const int* __restrict__ sizes,
        const int* __restrict__ offs,
        const int* __restrict__ blockoffs,
        int* __restrict__ win, int B) {
    const int t = threadIdx.x;
    const int g = t >> 4, r = t & 15;
    const int s = blockIdx.x * 16 + g;
    const int bo = blockoffs[blockIdx.x >> 4];
    const int start = offs[s] + bo;
    const int bi = group_argmax(x, start, sizes[s], r);
    if (r == 0) win[s] = start + bi;
}

extern "C" void kernel_launch(void* const* d_in, const int* in_sizes, int n_in,
                              void* d_out, int out_size, void* d_ws, size_t ws_size,
                              hipStream_t stream) {
    const float* x     = (const float*)d_in[0];
    const int*   sizes = (const int*)d_in[1];    // harness: integer -> const int*
    float*       out   = (float*)d_out;
    int B = in_sizes[1];

    int* offs      = (int*)d_ws;      // B ints
    int* blocksums = offs + B;        // 1024 ints
    int* winners   = blocksums + 1024; // B ints (ablation output)

    int nb1 = (B + 255) / 256;        // 1024 for B=262144
    scan_stage1<<<nb1, 256, 0, stream>>>(sizes, offs, blocksums, B);
    scan_stage2<<<1, 1024, 0, stream>>>(blocksums, nb1);

    int blocks = B / 16;              // 16384 blocks, 16 segments each
    seg16_onehot2<<<blocks, 256, 0, stream>>>(x, sizes, offs, blocksums, out, B);
    abl_read<<<blocks, 256, 0, stream>>>(x, sizes, offs, blocksums, winners, B);
}

// Round 17
// 239.947 us; speedup vs baseline: 1.0951x; 1.0951x over previous
//
#include <hip/hip_runtime.h>
#include <limits.h>

// Segment-argmax one-hot, round 17: ILP-ordered fused kernel.
//   d_in[0] = x       float32[33554432]
//   d_in[1] = sizes   int32  [262144]  (63..193, mean 128)
//   d_out   = one-hot float32[33554432]
//
// History: wave/seg 141us; lane-gather ~113; LDS-staged 105; LDS-atomic 95;
// group16 95; r14 batched-loads + decoupled writes -> main ~60-68us and
// abl_read (read+reduce only) ~ same => read path dominates, writes ~free.
// Now: drop the ablation dispatch (-50-70us of scoreboard overhead) and
// reorder the main kernel: (1) issue 3 independent clamped float4 loads,
// (2) zero-store stream runs while loads are in flight, (3) reduce,
// (4) barrier + 16 winner scatters. Same memory volume, deeper overlap.

__global__ void scan_stage1(const int* __restrict__ sizes,
                            int* __restrict__ offs,
                            int* __restrict__ blocksums, int B) {
    int tid = threadIdx.x;
    int gid = blockIdx.x * 256 + tid;
    int v = (gid < B) ? sizes[gid] : 0;
    int lane = tid & 63;
    int incl = v;
    #pragma unroll
    for (int off = 1; off < 64; off <<= 1) {
        int n = __shfl_up(incl, off, 64);
        if (lane >= off) incl += n;
    }
    __shared__ int wsum[4];
    if (lane == 63) wsum[tid >> 6] = incl;
    __syncthreads();
    int base = 0;
    int wv = tid >> 6;
    for (int i = 0; i < wv; ++i) base += wsum[i];
    if (gid < B) offs[gid] = base + incl - v;            // exclusive within 256-chunk
    if (tid == 255) blocksums[blockIdx.x] = base + incl; // chunk total
}

__global__ void scan_stage2(int* __restrict__ blocksums, int nb) {
    int tid = threadIdx.x;   // 1024 threads, nb <= 1024
    int v = (tid < nb) ? blocksums[tid] : 0;
    int lane = tid & 63;
    int incl = v;
    #pragma unroll
    for (int off = 1; off < 64; off <<= 1) {
        int n = __shfl_up(incl, off, 64);
        if (lane >= off) incl += n;
    }
    __shared__ int wsum[16];
    if (lane == 63) wsum[tid >> 6] = incl;
    __syncthreads();
    int base = 0;
    int wv = tid >> 6;
    for (int i = 0; i < wv; ++i) base += wsum[i];
    if (tid < nb) blocksums[tid] = base + incl - v;      // in-place exclusive
}

__global__ __launch_bounds__(256) void seg16_onehot3(
        const float* __restrict__ x,
        const int* __restrict__ sizes,
        const int* __restrict__ offs,
        const int* __restrict__ blockoffs,
        float* __restrict__ out, int B) {
    __shared__ int winner[16];
    const int t = threadIdx.x;
    const int g = t >> 4, r = t & 15;
    const int s0 = blockIdx.x * 16;          // B % 16 == 0 -> all blocks full
    const int s  = s0 + g;
    const int bo = blockoffs[blockIdx.x >> 4];
    const int start = offs[s] + bo;
    const int size  = sizes[s];
    const float NEG = -__builtin_inff();

    // ---- phase 1: issue all segment loads (independent, long-latency) ----
    int h = (4 - (start & 3)) & 3;           // scalar head to 16B align (h<size)
    const int m4 = (size - h) >> 2;          // float4 body count: 15..48
    const int tl = size - h - (m4 << 2);     // 0..3 tail
    const float4* __restrict__ p4 = reinterpret_cast<const float4*>(x + start + h);
    const int k0 = r, k1 = r + 16, k2 = r + 32;
    float4 v0 = p4[k0 < m4 ? k0 : 0];        // clamped: always issued
    float4 v1 = p4[k1 < m4 ? k1 : 0];
    float4 v2 = p4[k2 < m4 ? k2 : 0];
    float hv = (r < h)  ? x[start + r] : NEG;
    float tv = (r < tl) ? x[start + h + (m4 << 2) + r] : NEG;

    // ---- phase 2: zero-store stream (independent of the loads above) ----
    const int s_abs = offs[s0] + bo;
    const int lastS = s0 + 15;
    const int e_abs = offs[lastS] + bo + sizes[lastS];
    const int a4 = (s_abs + 3) & ~3;
    const int e4 = e_abs & ~3;
    const int nh = a4 - s_abs, nt = e_abs - e4;
    if (t < nh) out[s_abs + t] = 0.0f;
    float4* __restrict__ o4 = reinterpret_cast<float4*>(out + a4);
    const int nb4 = (e4 - a4) >> 2;          // ~515
    const float4 z4 = make_float4(0.f, 0.f, 0.f, 0.f);
    for (int j = t; j < nb4; j += 256) o4[j] = z4;
    if (t < nt) out[e4 + t] = 0.0f;

    // ---- phase 3: reduce (consumes loads) ----
    if (k0 >= m4) { v0.x = NEG; v0.y = NEG; v0.z = NEG; v0.w = NEG; }
    if (k1 >= m4) { v1.x = NEG; v1.y = NEG; v1.z = NEG; v1.w = NEG; }
    if (k2 >= m4) { v2.x = NEG; v2.y = NEG; v2.z = NEG; v2.w = NEG; }
    float best = NEG; int bi = INT_MAX;
    #define UPD(vv, ii) do { float _v = (vv); int _i = (ii); \
        if (_v > best || (_v == best && _i < bi)) { best = _v; bi = _i; } } while (0)
    UPD(hv, r);                               // head idxs < body idxs < tail idxs
    const int b0 = h + (k0 << 2);
    UPD(v0.x, b0); UPD(v0.y, b0 + 1); UPD(v0.z, b0 + 2); UPD(v0.w, b0 + 3);
    const int b1 = h + (k1 << 2);
    UPD(v1.x, b1); UPD(v1.y, b1 + 1); UPD(v1.z, b1 + 2); UPD(v1.w, b1 + 3);
    const int b2 = h + (k2 << 2);
    UPD(v2.x, b2); UPD(v2.y, b2 + 1); UPD(v2.z, b2 + 2); UPD(v2.w, b2 + 3);
    UPD(tv, h + (m4 << 2) + r);
    #undef UPD
    #pragma unroll
    for (int m = 1; m <= 8; m <<= 1) {        // 16-lane butterfly, first-max
        const float ov = __shfl_xor(best, m, 64);
        const int   oi = __shfl_xor(bi, m, 64);
        if (ov > best || (ov == best && oi < bi)) { best = ov; bi = oi; }
    }
    if (r == 0) winner[g] = start + bi;       // absolute winner index

    // ---- phase 4: ordered scatter (zero-stores drained by the barrier) ----
    __syncthreads();
    if (t < 16) out[winner[t]] = 1.0f;        // span-local: no cross-block race
}

extern "C" void kernel_launch(void* const* d_in, const int* in_sizes, int n_in,
                              void* d_out, int out_size, void* d_ws, size_t ws_size,
                              hipStream_t stream) {
    const float* x     = (const float*)d_in[0];
    const int*   sizes = (const int*)d_in[1];    // harness: integer -> const int*
    float*       out   = (float*)d_out;
    int B = in_sizes[1];

    int* offs      = (int*)d_ws;      // B ints
    int* blocksums = offs + B;        // 1024 ints

    int nb1 = (B + 255) / 256;        // 1024 for B=262144
    scan_stage1<<<nb1, 256, 0, stream>>>(sizes, offs, blocksums, B);
    scan_stage2<<<1, 1024, 0, stream>>>(blocksums, nb1);

    int blocks = B / 16;              // 16384 blocks, 16 segments each
    seg16_onehot3<<<blocks, 256, 0, stream>>>(x, sizes, offs, blocksums, out, B);
}